// Round 2
// baseline (270.358 us; speedup 1.0000x reference)
//
#include <hip/hip_runtime.h>
#include <hip/hip_bf16.h>

typedef __hip_bfloat16 bf16;
typedef __attribute__((ext_vector_type(8))) short bf16x8;
typedef __attribute__((ext_vector_type(4))) float f32x4;

// Geometry (hardcoded): B=2, T=16, H=32, W=32, C=512, heads=8, hd=64,
// win=(8,8,8) -> no padding. 64 windows x 512 tokens; M = 32768 rows.
#define MROWS 32768
#define CDIM 512
#define SEL_STRIDE (512*512*64)  // elems per q/k/v section
// q,k sections: [wh=512][tok=512][d=64] row-major
// v section:    [wh=512][d=64][tok=512]  (TRANSPOSED by the QKV GEMM epilogue)

__device__ __forceinline__ int win_to_src_row(int m) {
  int win = m >> 9, l = m & 511;
  int b = win >> 5, rr = win & 31;
  int nt = rr >> 4, nh = (rr >> 2) & 3, nw = rr & 3;
  int wt = l >> 6, wh = (l >> 3) & 7, ww = l & 7;
  int tt = nt * 8 + wt, hh = nh * 8 + wh, wp = nw * 8 + ww;
  return (b << 14) + (tt << 10) + (hh << 5) + wp;
}

__device__ __forceinline__ unsigned short bf16bits(bf16 h) {
  return __builtin_bit_cast(unsigned short, h);
}

// XCD-chunked bijective block swizzle (requires n % 8 == 0)
__device__ __forceinline__ int xcd_chunk(int bx, int n) {
  return (bx & 7) * (n >> 3) + (bx >> 3);
}

// ---------------- pass 0a: weight transpose + fp32->bf16 ----------------
__global__ __launch_bounds__(256) void transpose_cvt_kernel(
    const float* __restrict__ src, bf16* __restrict__ dst, int R, int C) {
  __shared__ float tile[32][33];
  int bc = blockIdx.x * 32, br = blockIdx.y * 32;
  int tx = threadIdx.x, ty = threadIdx.y;  // (32,8)
#pragma unroll
  for (int i = 0; i < 32; i += 8)
    tile[ty + i][tx] = src[(size_t)(br + ty + i) * C + bc + tx];
  __syncthreads();
#pragma unroll
  for (int i = 0; i < 32; i += 8)
    dst[(size_t)(bc + ty + i) * R + br + tx] = __float2bfloat16(tile[tx][ty + i]);
}

// ---------------- pass 0b: x permute to window order + fp32->bf16 ----------------
__global__ __launch_bounds__(256) void perm_x_kernel(const float* __restrict__ x,
                                                     bf16* __restrict__ xw) {
  const int total = MROWS * (CDIM / 4);  // float4 units
  for (int i = blockIdx.x * 256 + threadIdx.x; i < total; i += 2048 * 256) {
    int m = i >> 7, c4 = (i & 127) * 4;
    int src = win_to_src_row(m);
    float4 v = *(const float4*)(x + (size_t)src * CDIM + c4);
    ushort4 o;
    o.x = bf16bits(__float2bfloat16(v.x));
    o.y = bf16bits(__float2bfloat16(v.y));
    o.z = bf16bits(__float2bfloat16(v.z));
    o.w = bf16bits(__float2bfloat16(v.w));
    *(ushort4*)(xw + (size_t)m * CDIM + c4) = o;
  }
}

// ---------------- shared GEMM: C[M,N] = A[M,512] @ Bt[N,512]^T ----------------
#define BM 128
#define BN 128
#define BK 64

__device__ __forceinline__ void gload16(const bf16* g, bf16* l) {
  __builtin_amdgcn_global_load_lds(
      (const __attribute__((address_space(1))) unsigned int*)g,
      (__attribute__((address_space(3))) unsigned int*)l, 16, 0, 0);
}

// MODE 0: QKV (q,k row-major scatter; v TRANSPOSED scatter with packed stores)
// MODE 1: proj (fp32 d_out with window un-partition + bias)
template <int MODE>
__global__ __launch_bounds__(256) void gemm_bt_kernel(
    const bf16* __restrict__ A, const bf16* __restrict__ Bt, int Ntiles,
    bf16* __restrict__ qkv_out, float* __restrict__ out,
    const float* __restrict__ bias) {
  __shared__ __align__(16) bf16 Asl[BM * BK];
  __shared__ __align__(16) bf16 Bsl[BN * BK];
  const int K = 512;
  int l2 = xcd_chunk(blockIdx.x, gridDim.x);
  int bn = (l2 >> 3) % Ntiles;
  int bm = (l2 & 7) + (l2 / (8 * Ntiles)) * 8;
  int t = threadIdx.x, lane = t & 63, w = t >> 6;
  int wr = w >> 1, wc = w & 1;  // 2x2 waves, 64x64 each
  int l15 = lane & 15, lh = lane >> 4;
  f32x4 acc[4][4] = {};

  for (int kt = 0; kt < K; kt += BK) {
    __syncthreads();
#pragma unroll
    for (int i = 0; i < 4; ++i) {
      int f = i * 256 + t;
      int row = f >> 3, cb = f & 7;
      gload16(A + (size_t)(bm * BM + row) * K + kt + cb * 8,
              &Asl[(i * 256 + w * 64) * 8]);
    }
#pragma unroll
    for (int i = 0; i < 4; ++i) {
      int f = i * 256 + t;
      int row = f >> 3, cb = f & 7;
      gload16(Bt + (size_t)(bn * BN + row) * K + kt + cb * 8,
              &Bsl[(i * 256 + w * 64) * 8]);
    }
    __syncthreads();
#pragma unroll
    for (int kk = 0; kk < 2; ++kk) {
      bf16x8 af[4], bfr[4];
#pragma unroll
      for (int mi = 0; mi < 4; ++mi)
        af[mi] = *(const bf16x8*)&Asl[(wr * 64 + mi * 16 + l15) * BK + kk * 32 + lh * 8];
#pragma unroll
      for (int nj = 0; nj < 4; ++nj)
        bfr[nj] = *(const bf16x8*)&Bsl[(wc * 64 + nj * 16 + l15) * BK + kk * 32 + lh * 8];
#pragma unroll
      for (int mi = 0; mi < 4; ++mi)
#pragma unroll
        for (int nj = 0; nj < 4; ++nj)
          acc[mi][nj] = __builtin_amdgcn_mfma_f32_16x16x32_bf16(
              af[mi], bfr[nj], acc[mi][nj], 0, 0, 0);
    }
  }

  if (MODE == 0) {
#pragma unroll
    for (int mi = 0; mi < 4; ++mi) {
      int row = bm * BM + wr * 64 + mi * 16 + lh * 4;  // 4-aligned, never crosses win
      int win = row >> 9, tok = row & 511;
#pragma unroll
      for (int nj = 0; nj < 4; ++nj) {
        int col = bn * BN + wc * 64 + nj * 16 + l15;
        int sel = col >> 9, cc = col & 511;
        int head = cc >> 6, d = cc & 63;
        if (sel == 2) {
          // transposed: [wh][d][tok], 4 consecutive toks -> one 8B store
          ushort4 pk;
          pk.x = bf16bits(__float2bfloat16(acc[mi][nj][0]));
          pk.y = bf16bits(__float2bfloat16(acc[mi][nj][1]));
          pk.z = bf16bits(__float2bfloat16(acc[mi][nj][2]));
          pk.w = bf16bits(__float2bfloat16(acc[mi][nj][3]));
          *(ushort4*)(qkv_out + 2 * (size_t)SEL_STRIDE +
                      (((size_t)(win * 8 + head)) * 64 + d) * 512 + tok) = pk;
        } else {
          size_t base = (size_t)sel * SEL_STRIDE +
                        (((size_t)(win * 8 + head)) * 512 + tok) * 64 + d;
#pragma unroll
          for (int r = 0; r < 4; ++r)
            qkv_out[base + (size_t)r * 64] = __float2bfloat16(acc[mi][nj][r]);
        }
      }
    }
  } else {
#pragma unroll
    for (int mi = 0; mi < 4; ++mi) {
      int row = bm * BM + wr * 64 + mi * 16 + lh * 4;
#pragma unroll
      for (int r = 0; r < 4; ++r) {
        int srow = win_to_src_row(row + r);
        float* op = out + (size_t)srow * CDIM;
#pragma unroll
        for (int nj = 0; nj < 4; ++nj) {
          int col = bn * BN + wc * 64 + nj * 16 + l15;
          op[col] = acc[mi][nj][r] + bias[col];
        }
      }
    }
  }
}

// ---------------- pass 2: windowed attention (flash-tiled, LDS = P only) ----------
// grid = 2048 blocks = (wh=512) x (qc=4 tiles of 128 rows); 256 threads = 4 waves,
// each wave owns 32 q-rows. K read direct from global (row-major, coalesced);
// V read direct from global V^T section. No __syncthreads anywhere.
__global__ __launch_bounds__(256) void attn_kernel(const bf16* __restrict__ qkv_ws,
                                                   bf16* __restrict__ o_ws) {
  __shared__ __align__(16) bf16 Pl[4][16 * 64];  // per-wave P tile, swizzled
  int l2 = xcd_chunk(blockIdx.x, 2048);
  int wh = l2 >> 2, qc = l2 & 3;
  int win = wh >> 3, head = wh & 7;
  int t = threadIdx.x, lane = t & 63, w = t >> 6;
  int l15 = lane & 15, lh = lane >> 4;
  const bf16* qb = qkv_ws + (size_t)wh * (512 * 64);
  const bf16* kb = qb + SEL_STRIDE;
  const bf16* vtb = qkv_ws + 2 * (size_t)SEL_STRIDE + (size_t)wh * (64 * 512);

  const float scale = 0.125f;
  int q0 = qc * 128 + w * 32;
  bf16x8 qf[2][2];
#pragma unroll
  for (int qi = 0; qi < 2; ++qi)
#pragma unroll
    for (int kk = 0; kk < 2; ++kk)
      qf[qi][kk] = *(const bf16x8*)(qb + (size_t)(q0 + qi * 16 + l15) * 64 + kk * 32 + lh * 8);

  f32x4 acco[2][4] = {};
  float lsum[2][4] = {};
  for (int kt = 0; kt < 8; ++kt) {
    bf16x8 kf[4][2], vf[4][2];
#pragma unroll
    for (int kj = 0; kj < 4; ++kj) {
      int tok = kt * 64 + kj * 16 + l15;
#pragma unroll
      for (int kk = 0; kk < 2; ++kk)
        kf[kj][kk] = *(const bf16x8*)(kb + (size_t)tok * 64 + kk * 32 + lh * 8);
    }
#pragma unroll
    for (int nj = 0; nj < 4; ++nj) {
      int d = nj * 16 + l15;
#pragma unroll
      for (int kk = 0; kk < 2; ++kk)
        vf[nj][kk] = *(const bf16x8*)(vtb + (size_t)d * 512 + kt * 64 + kk * 32 + lh * 8);
    }
#pragma unroll
    for (int qi = 0; qi < 2; ++qi) {
      f32x4 s[4] = {};
#pragma unroll
      for (int kj = 0; kj < 4; ++kj)
#pragma unroll
        for (int kk = 0; kk < 2; ++kk)
          s[kj] = __builtin_amdgcn_mfma_f32_16x16x32_bf16(qf[qi][kk], kf[kj][kk], s[kj], 0, 0, 0);
      float rs[4] = {0.f, 0.f, 0.f, 0.f};
#pragma unroll
      for (int kj = 0; kj < 4; ++kj)
#pragma unroll
        for (int r = 0; r < 4; ++r) {
          float p = __expf(s[kj][r] * scale);
          s[kj][r] = p;
          rs[r] += p;
        }
#pragma unroll
      for (int r = 0; r < 4; ++r) {
        float v = rs[r];
        v += __shfl_xor(v, 1);
        v += __shfl_xor(v, 2);
        v += __shfl_xor(v, 4);
        v += __shfl_xor(v, 8);
        lsum[qi][r] += v;
      }
#pragma unroll
      for (int kj = 0; kj < 4; ++kj)
#pragma unroll
        for (int r = 0; r < 4; ++r) {
          int prow = lh * 4 + r, pcol = kj * 16 + l15;
          *(bf16*)((char*)&Pl[w][0] + prow * 128 + ((pcol * 2) ^ ((prow & 7) << 4))) =
              __float2bfloat16(s[kj][r]);
        }
      bf16x8 pa[2];
#pragma unroll
      for (int kk = 0; kk < 2; ++kk)
        pa[kk] = *(const bf16x8*)((const char*)&Pl[w][0] + l15 * 128 +
                                  ((kk * 64 + lh * 16) ^ ((l15 & 7) << 4)));
#pragma unroll
      for (int nj = 0; nj < 4; ++nj)
#pragma unroll
        for (int kk = 0; kk < 2; ++kk)
          acco[qi][nj] = __builtin_amdgcn_mfma_f32_16x16x32_bf16(pa[kk], vf[nj][kk],
                                                                 acco[qi][nj], 0, 0, 0);
    }
  }
#pragma unroll
  for (int qi = 0; qi < 2; ++qi) {
    float inv[4];
#pragma unroll
    for (int r = 0; r < 4; ++r) inv[r] = __frcp_rn(lsum[qi][r]);
#pragma unroll
    for (int nj = 0; nj < 4; ++nj)
#pragma unroll
      for (int r = 0; r < 4; ++r) {
        int row = q0 + qi * 16 + lh * 4 + r;
        int d = nj * 16 + l15;
        o_ws[((size_t)win * 512 + row) * 512 + head * 64 + d] =
            __float2bfloat16(acco[qi][nj][r] * inv[r]);
      }
  }
}

extern "C" void kernel_launch(void* const* d_in, const int* in_sizes, int n_in,
                              void* d_out, int out_size, void* d_ws, size_t ws_size,
                              hipStream_t stream) {
  const float* x = (const float*)d_in[0];
  const float* w_qkv = (const float*)d_in[1];
  const float* w_proj = (const float*)d_in[2];
  const float* b_proj = (const float*)d_in[3];
  float* out = (float*)d_out;

  const size_t OFF_QKV = 33554432;
  const size_t OFF_WQ = OFF_QKV + 100663296;
  const size_t OFF_WP = OFF_WQ + 1572864;
  const size_t NEED = OFF_WP + 524288;
  if (ws_size < NEED) return;

  char* ws = (char*)d_ws;
  bf16* xw = (bf16*)ws;
  bf16* qkv = (bf16*)(ws + OFF_QKV);
  bf16* wqkvT = (bf16*)(ws + OFF_WQ);
  bf16* wprojT = (bf16*)(ws + OFF_WP);
  bf16* o_ws = xw;  // attention does not read xw

  transpose_cvt_kernel<<<dim3(1536 / 32, 512 / 32), dim3(32, 8), 0, stream>>>(w_qkv, wqkvT, 512, 1536);
  transpose_cvt_kernel<<<dim3(512 / 32, 512 / 32), dim3(32, 8), 0, stream>>>(w_proj, wprojT, 512, 512);
  perm_x_kernel<<<2048, 256, 0, stream>>>(x, xw);
  gemm_bt_kernel<0><<<256 * 12, 256, 0, stream>>>(xw, wqkvT, 12, qkv, nullptr, nullptr);
  attn_kernel<<<2048, 256, 0, stream>>>(qkv, o_ws);
  gemm_bt_kernel<1><<<256 * 4, 256, 0, stream>>>(o_ws, wprojT, 4, nullptr, out, b_proj);
}

// Round 3
// 233.318 us; speedup vs baseline: 1.1588x; 1.1588x over previous
//
#include <hip/hip_runtime.h>
#include <hip/hip_bf16.h>

typedef __hip_bfloat16 bf16;
typedef __attribute__((ext_vector_type(8))) short bf16x8;
typedef __attribute__((ext_vector_type(4))) float f32x4;

// Geometry (hardcoded): B=2, T=16, H=32, W=32, C=512, heads=8, hd=64,
// win=(8,8,8) -> no padding. 64 windows x 512 tokens; M = 32768 rows.
#define MROWS 32768
#define CDIM 512
#define SEL_STRIDE (512*512*64)  // elems per q/k/v section
// q,k sections: [wh=512][tok=512][d=64] row-major
// v section:    [wh=512][d=64][tok=512]  (TRANSPOSED by the QKV GEMM epilogue)

__device__ __forceinline__ int win_to_src_row(int m) {
  int win = m >> 9, l = m & 511;
  int b = win >> 5, rr = win & 31;
  int nt = rr >> 4, nh = (rr >> 2) & 3, nw = rr & 3;
  int wt = l >> 6, wh = (l >> 3) & 7, ww = l & 7;
  int tt = nt * 8 + wt, hh = nh * 8 + wh, wp = nw * 8 + ww;
  return (b << 14) + (tt << 10) + (hh << 5) + wp;
}

__device__ __forceinline__ unsigned short bf16bits(bf16 h) {
  return __builtin_bit_cast(unsigned short, h);
}

// XCD-chunked bijective block swizzle (requires n % 8 == 0)
__device__ __forceinline__ int xcd_chunk(int bx, int n) {
  return (bx & 7) * (n >> 3) + (bx >> 3);
}

// ---------------- pass 0a: weight transpose + fp32->bf16 ----------------
__global__ __launch_bounds__(256) void transpose_cvt_kernel(
    const float* __restrict__ src, bf16* __restrict__ dst, int R, int C) {
  __shared__ float tile[32][33];
  int bc = blockIdx.x * 32, br = blockIdx.y * 32;
  int tx = threadIdx.x, ty = threadIdx.y;  // (32,8)
#pragma unroll
  for (int i = 0; i < 32; i += 8)
    tile[ty + i][tx] = src[(size_t)(br + ty + i) * C + bc + tx];
  __syncthreads();
#pragma unroll
  for (int i = 0; i < 32; i += 8)
    dst[(size_t)(bc + ty + i) * R + br + tx] = __float2bfloat16(tile[tx][ty + i]);
}

// ---------------- pass 0b: x permute to window order + fp32->bf16 ----------------
__global__ __launch_bounds__(256) void perm_x_kernel(const float* __restrict__ x,
                                                     bf16* __restrict__ xw) {
  const int total = MROWS * (CDIM / 4);  // float4 units
  for (int i = blockIdx.x * 256 + threadIdx.x; i < total; i += 2048 * 256) {
    int m = i >> 7, c4 = (i & 127) * 4;
    int src = win_to_src_row(m);
    float4 v = *(const float4*)(x + (size_t)src * CDIM + c4);
    ushort4 o;
    o.x = bf16bits(__float2bfloat16(v.x));
    o.y = bf16bits(__float2bfloat16(v.y));
    o.z = bf16bits(__float2bfloat16(v.z));
    o.w = bf16bits(__float2bfloat16(v.w));
    *(ushort4*)(xw + (size_t)m * CDIM + c4) = o;
  }
}

// ---------------- shared GEMM: C[M,N] = A[M,512] @ Bt[N,512]^T ----------------
#define BM 128
#define BN 128
#define BK 64

__device__ __forceinline__ void gload16(const bf16* g, bf16* l) {
  __builtin_amdgcn_global_load_lds(
      (const __attribute__((address_space(1))) unsigned int*)g,
      (__attribute__((address_space(3))) unsigned int*)l, 16, 0, 0);
}

// MODE 0: QKV (q,k row-major scatter; v TRANSPOSED scatter with packed stores)
// MODE 1: proj (fp32 d_out with window un-partition + bias)
template <int MODE>
__global__ __launch_bounds__(256) void gemm_bt_kernel(
    const bf16* __restrict__ A, const bf16* __restrict__ Bt, int Ntiles,
    bf16* __restrict__ qkv_out, float* __restrict__ out,
    const float* __restrict__ bias) {
  __shared__ __align__(16) bf16 Asl[BM * BK];
  __shared__ __align__(16) bf16 Bsl[BN * BK];
  const int K = 512;
  int l2 = xcd_chunk(blockIdx.x, gridDim.x);
  int bn = (l2 >> 3) % Ntiles;
  int bm = (l2 & 7) + (l2 / (8 * Ntiles)) * 8;
  int t = threadIdx.x, lane = t & 63, w = t >> 6;
  int wr = w >> 1, wc = w & 1;  // 2x2 waves, 64x64 each
  int l15 = lane & 15, lh = lane >> 4;
  f32x4 acc[4][4] = {};

  for (int kt = 0; kt < K; kt += BK) {
    __syncthreads();
#pragma unroll
    for (int i = 0; i < 4; ++i) {
      int f = i * 256 + t;
      int row = f >> 3, cb = f & 7;
      gload16(A + (size_t)(bm * BM + row) * K + kt + cb * 8,
              &Asl[(i * 256 + w * 64) * 8]);
    }
#pragma unroll
    for (int i = 0; i < 4; ++i) {
      int f = i * 256 + t;
      int row = f >> 3, cb = f & 7;
      gload16(Bt + (size_t)(bn * BN + row) * K + kt + cb * 8,
              &Bsl[(i * 256 + w * 64) * 8]);
    }
    __syncthreads();
#pragma unroll
    for (int kk = 0; kk < 2; ++kk) {
      bf16x8 af[4], bfr[4];
#pragma unroll
      for (int mi = 0; mi < 4; ++mi)
        af[mi] = *(const bf16x8*)&Asl[(wr * 64 + mi * 16 + l15) * BK + kk * 32 + lh * 8];
#pragma unroll
      for (int nj = 0; nj < 4; ++nj)
        bfr[nj] = *(const bf16x8*)&Bsl[(wc * 64 + nj * 16 + l15) * BK + kk * 32 + lh * 8];
#pragma unroll
      for (int mi = 0; mi < 4; ++mi)
#pragma unroll
        for (int nj = 0; nj < 4; ++nj)
          acc[mi][nj] = __builtin_amdgcn_mfma_f32_16x16x32_bf16(
              af[mi], bfr[nj], acc[mi][nj], 0, 0, 0);
    }
  }

  if (MODE == 0) {
#pragma unroll
    for (int mi = 0; mi < 4; ++mi) {
      int row = bm * BM + wr * 64 + mi * 16 + lh * 4;  // 4-aligned, never crosses win
      int win = row >> 9, tok = row & 511;
#pragma unroll
      for (int nj = 0; nj < 4; ++nj) {
        int col = bn * BN + wc * 64 + nj * 16 + l15;
        int sel = col >> 9, cc = col & 511;
        int head = cc >> 6, d = cc & 63;
        if (sel == 2) {
          // transposed: [wh][d][tok], 4 consecutive toks -> one 8B store
          ushort4 pk;
          pk.x = bf16bits(__float2bfloat16(acc[mi][nj][0]));
          pk.y = bf16bits(__float2bfloat16(acc[mi][nj][1]));
          pk.z = bf16bits(__float2bfloat16(acc[mi][nj][2]));
          pk.w = bf16bits(__float2bfloat16(acc[mi][nj][3]));
          *(ushort4*)(qkv_out + 2 * (size_t)SEL_STRIDE +
                      (((size_t)(win * 8 + head)) * 64 + d) * 512 + tok) = pk;
        } else {
          size_t base = (size_t)sel * SEL_STRIDE +
                        (((size_t)(win * 8 + head)) * 512 + tok) * 64 + d;
#pragma unroll
          for (int r = 0; r < 4; ++r)
            qkv_out[base + (size_t)r * 64] = __float2bfloat16(acc[mi][nj][r]);
        }
      }
    }
  } else {
#pragma unroll
    for (int mi = 0; mi < 4; ++mi) {
      int row = bm * BM + wr * 64 + mi * 16 + lh * 4;
#pragma unroll
      for (int r = 0; r < 4; ++r) {
        int srow = win_to_src_row(row + r);
        float* op = out + (size_t)srow * CDIM;
#pragma unroll
        for (int nj = 0; nj < 4; ++nj) {
          int col = bn * BN + wc * 64 + nj * 16 + l15;
          op[col] = acc[mi][nj][r] + bias[col];
        }
      }
    }
  }
}

// ---------------- pass 2: windowed attention ----------------
// grid = 1024 blocks = (wh=512) x (qc=2 tiles of 256 rows); 256 threads = 4 waves.
// Each wave owns 64 q-rows (qi=0..3) -> K/V fragment loads amortized 4x, and the
// four independent qi chains give ILP to cover global/LDS latency.
// K direct from global (row-major); V direct from the transposed V section.
__global__ __launch_bounds__(256, 2) void attn_kernel(const bf16* __restrict__ qkv_ws,
                                                      bf16* __restrict__ o_ws) {
  __shared__ __align__(16) bf16 Pl[4][4][16 * 64];  // [wave][qi] P tiles, swizzled
  int l2 = xcd_chunk(blockIdx.x, 1024);
  int wh = l2 >> 1, qc = l2 & 1;
  int win = wh >> 3, head = wh & 7;
  int t = threadIdx.x, lane = t & 63, w = t >> 6;
  int l15 = lane & 15, lh = lane >> 4;
  const bf16* qb = qkv_ws + (size_t)wh * (512 * 64);
  const bf16* kb = qb + SEL_STRIDE;
  const bf16* vtb = qkv_ws + 2 * (size_t)SEL_STRIDE + (size_t)wh * (64 * 512);

  const float c_scale = 0.18033688011112042f;  // 0.125 * log2(e)
  int q0 = qc * 256 + w * 64;
  bf16x8 qf[4][2];
#pragma unroll
  for (int qi = 0; qi < 4; ++qi)
#pragma unroll
    for (int kk = 0; kk < 2; ++kk)
      qf[qi][kk] = *(const bf16x8*)(qb + (size_t)(q0 + qi * 16 + l15) * 64 + kk * 32 + lh * 8);

  f32x4 acco[4][4] = {};
  float lsum[4][4] = {};
  for (int kt = 0; kt < 8; ++kt) {
    bf16x8 kf[4][2], vf[4][2];
#pragma unroll
    for (int kj = 0; kj < 4; ++kj) {
      int tok = kt * 64 + kj * 16 + l15;
#pragma unroll
      for (int kk = 0; kk < 2; ++kk)
        kf[kj][kk] = *(const bf16x8*)(kb + (size_t)tok * 64 + kk * 32 + lh * 8);
    }
#pragma unroll
    for (int nj = 0; nj < 4; ++nj) {
      int d = nj * 16 + l15;
#pragma unroll
      for (int kk = 0; kk < 2; ++kk)
        vf[nj][kk] = *(const bf16x8*)(vtb + (size_t)d * 512 + kt * 64 + kk * 32 + lh * 8);
    }
#pragma unroll
    for (int qi = 0; qi < 4; ++qi) {
      f32x4 s[4] = {};
#pragma unroll
      for (int kj = 0; kj < 4; ++kj)
#pragma unroll
        for (int kk = 0; kk < 2; ++kk)
          s[kj] = __builtin_amdgcn_mfma_f32_16x16x32_bf16(qf[qi][kk], kf[kj][kk], s[kj], 0, 0, 0);
      // exp2-based softmax numerator; per-lane partial row-sums (cross-lane
      // reduce hoisted out of the k-loop).
#pragma unroll
      for (int kj = 0; kj < 4; ++kj)
#pragma unroll
        for (int r = 0; r < 4; ++r) {
          float p = __builtin_exp2f(s[kj][r] * c_scale);
          s[kj][r] = p;
          lsum[qi][r] += p;
        }
#pragma unroll
      for (int kj = 0; kj < 4; ++kj)
#pragma unroll
        for (int r = 0; r < 4; ++r) {
          int prow = lh * 4 + r, pcol = kj * 16 + l15;
          *(bf16*)((char*)&Pl[w][qi][0] + prow * 128 + ((pcol * 2) ^ ((prow & 7) << 4))) =
              __float2bfloat16(s[kj][r]);
        }
      bf16x8 pa[2];
#pragma unroll
      for (int kk = 0; kk < 2; ++kk)
        pa[kk] = *(const bf16x8*)((const char*)&Pl[w][qi][0] + l15 * 128 +
                                  ((kk * 64 + lh * 16) ^ ((l15 & 7) << 4)));
#pragma unroll
      for (int nj = 0; nj < 4; ++nj)
#pragma unroll
        for (int kk = 0; kk < 2; ++kk)
          acco[qi][nj] = __builtin_amdgcn_mfma_f32_16x16x32_bf16(pa[kk], vf[nj][kk],
                                                                 acco[qi][nj], 0, 0, 0);
    }
  }
  // final cross-lane reduce of the row sums (sum over l15 groups), then store
#pragma unroll
  for (int qi = 0; qi < 4; ++qi) {
    float inv[4];
#pragma unroll
    for (int r = 0; r < 4; ++r) {
      float v = lsum[qi][r];
      v += __shfl_xor(v, 1);
      v += __shfl_xor(v, 2);
      v += __shfl_xor(v, 4);
      v += __shfl_xor(v, 8);
      inv[r] = __frcp_rn(v);
    }
#pragma unroll
    for (int nj = 0; nj < 4; ++nj)
#pragma unroll
      for (int r = 0; r < 4; ++r) {
        int row = q0 + qi * 16 + lh * 4 + r;
        int d = nj * 16 + l15;
        o_ws[((size_t)win * 512 + row) * 512 + head * 64 + d] =
            __float2bfloat16(acco[qi][nj][r] * inv[r]);
      }
  }
}

extern "C" void kernel_launch(void* const* d_in, const int* in_sizes, int n_in,
                              void* d_out, int out_size, void* d_ws, size_t ws_size,
                              hipStream_t stream) {
  const float* x = (const float*)d_in[0];
  const float* w_qkv = (const float*)d_in[1];
  const float* w_proj = (const float*)d_in[2];
  const float* b_proj = (const float*)d_in[3];
  float* out = (float*)d_out;

  const size_t OFF_QKV = 33554432;
  const size_t OFF_WQ = OFF_QKV + 100663296;
  const size_t OFF_WP = OFF_WQ + 1572864;
  const size_t NEED = OFF_WP + 524288;
  if (ws_size < NEED) return;

  char* ws = (char*)d_ws;
  bf16* xw = (bf16*)ws;
  bf16* qkv = (bf16*)(ws + OFF_QKV);
  bf16* wqkvT = (bf16*)(ws + OFF_WQ);
  bf16* wprojT = (bf16*)(ws + OFF_WP);
  bf16* o_ws = xw;  // attention does not read xw

  transpose_cvt_kernel<<<dim3(1536 / 32, 512 / 32), dim3(32, 8), 0, stream>>>(w_qkv, wqkvT, 512, 1536);
  transpose_cvt_kernel<<<dim3(512 / 32, 512 / 32), dim3(32, 8), 0, stream>>>(w_proj, wprojT, 512, 512);
  perm_x_kernel<<<2048, 256, 0, stream>>>(x, xw);
  gemm_bt_kernel<0><<<256 * 12, 256, 0, stream>>>(xw, wqkvT, 12, qkv, nullptr, nullptr);
  attn_kernel<<<1024, 256, 0, stream>>>(qkv, o_ws);
  gemm_bt_kernel<1><<<256 * 4, 256, 0, stream>>>(o_ws, wprojT, 4, nullptr, out, b_proj);
}